// Round 1
// baseline (813.566 us; speedup 1.0000x reference)
//
#include <hip/hip_runtime.h>
#include <math.h>

// ConvCapsuleLayer: fused conv(5x5 SAME, shared over capsules) + 3-iter dynamic routing.
// One 256-thread block per (b', h, w) output position; 16384 blocks total.
// Scrambled batch mapping (faithful to reference reshape):
//   votes[b', i'] comes from x sample  i_x = b' >> 1,  b_x = ((b'&1)<<3) + i'.

__global__ __launch_bounds__(256) void caps_fused_kernel(
    const float* __restrict__ xg,    // [16,32,32,8,16]
    const float* __restrict__ wg,    // [5,5,16,256] == [400][256] row-major
    const float* __restrict__ bg,    // [256]
    float* __restrict__ outg)        // [16,32,32,16,16]
{
    __shared__ float xs[400 * 8];      // [p][i], p = (kh*5+kw)*16 + c
    __shared__ float votes_s[8 * 256]; // [i][od]
    __shared__ float act_s[256];
    __shared__ float logit_s[128];     // [i][o]
    __shared__ float route_s[128];     // [i][o]
    __shared__ float bias_s[256];

    const int t     = threadIdx.x;
    const int blk   = blockIdx.x;
    const int w0    = blk & 31;
    const int h0    = (blk >> 5) & 31;
    const int bp    = blk >> 10;       // b'
    const int i_x   = bp >> 1;
    const int bbase = (bp & 1) << 3;

    // ---- stage x window into LDS: xs[p*8+i] = x[bbase+i, h0+kh-2, w0+kw-2, i_x, c]
    for (int idx = t; idx < 3200; idx += 256) {
        int i  = idx & 7;
        int p  = idx >> 3;
        int kh = p / 80;               // p / (5*16)
        int r  = p - kh * 80;
        int kw = r >> 4;
        int c  = r & 15;
        int hh = h0 + kh - 2;
        int ww = w0 + kw - 2;
        float v = 0.0f;
        if (hh >= 0 && hh < 32 && ww >= 0 && ww < 32) {
            int b_x = bbase + i;
            v = xg[(((b_x * 32 + hh) * 32 + ww) * 8 + i_x) * 16 + c];
        }
        xs[idx] = v;
    }
    bias_s[t] = bg[t];
    if (t < 128) logit_s[t] = 0.0f;
    __syncthreads();

    // ---- conv: wave wv handles i = {2wv, 2wv+1}; lane handles od = lane*4 .. lane*4+3
    const int wv   = t >> 6;
    const int lane = t & 63;
    float acc[8];
    #pragma unroll
    for (int j = 0; j < 8; ++j) acc[j] = 0.0f;

    const float4* w4  = (const float4*)wg;   // [400][64]
    const float2* xs2 = (const float2*)xs;   // [400][4]

    for (int p4 = 0; p4 < 100; ++p4) {
        float2 xv[4];
        float4 wvv[4];
        #pragma unroll
        for (int j = 0; j < 4; ++j) {
            int p  = p4 * 4 + j;
            xv[j]  = xs2[p * 4 + wv];        // broadcast read (wave-uniform addr)
            wvv[j] = w4[p * 64 + lane];      // coalesced 16B/lane from L2
        }
        #pragma unroll
        for (int j = 0; j < 4; ++j) {
            acc[0] += xv[j].x * wvv[j].x;
            acc[1] += xv[j].x * wvv[j].y;
            acc[2] += xv[j].x * wvv[j].z;
            acc[3] += xv[j].x * wvv[j].w;
            acc[4] += xv[j].y * wvv[j].x;
            acc[5] += xv[j].y * wvv[j].y;
            acc[6] += xv[j].y * wvv[j].z;
            acc[7] += xv[j].y * wvv[j].w;
        }
    }

    // write votes to LDS
    {
        float4 v0 = make_float4(acc[0], acc[1], acc[2], acc[3]);
        float4 v1 = make_float4(acc[4], acc[5], acc[6], acc[7]);
        *(float4*)&votes_s[(2 * wv) * 256 + lane * 4]     = v0;
        *(float4*)&votes_s[(2 * wv + 1) * 256 + lane * 4] = v1;
    }
    __syncthreads();

    // ---- routing: 3 iterations; thread t owns output element od = t (o = t>>4, d = t&15)
    const int o = t >> 4;
    float act = 0.0f;
    for (int it = 0; it < 3; ++it) {
        // softmax over o for each i (8 rows; cheap, done by threads 0..7)
        if (t < 8) {
            float m = -1e30f;
            #pragma unroll
            for (int oo = 0; oo < 16; ++oo) m = fmaxf(m, logit_s[t * 16 + oo]);
            float e[16];
            float s = 0.0f;
            #pragma unroll
            for (int oo = 0; oo < 16; ++oo) { e[oo] = expf(logit_s[t * 16 + oo] - m); s += e[oo]; }
            float inv = 1.0f / s;
            #pragma unroll
            for (int oo = 0; oo < 16; ++oo) route_s[t * 16 + oo] = e[oo] * inv;
        }
        __syncthreads();

        // preact[od] = sum_i route[i][o] * votes[i][od] + bias[od]
        float pre = bias_s[t];
        #pragma unroll
        for (int i = 0; i < 8; ++i) pre += route_s[i * 16 + o] * votes_s[i * 256 + t];

        // squash: n2 over the 16 d-lanes of this o (contiguous 16-lane groups)
        float n2 = pre * pre;
        #pragma unroll
        for (int off = 8; off >= 1; off >>= 1) n2 += __shfl_xor(n2, off, 16);
        act = pre * sqrtf(n2) / (1.0f + n2);

        if (it < 2) {
            act_s[t] = act;
            __syncthreads();
            // logits[i][o] += sum_d votes[i][o*16+d] * act[o*16+d]
            if (t < 128) {
                int ii = t >> 4;
                int oo = t & 15;
                float s = 0.0f;
                #pragma unroll
                for (int dd = 0; dd < 16; ++dd)
                    s += votes_s[ii * 256 + oo * 16 + dd] * act_s[oo * 16 + dd];
                logit_s[t] += s;
            }
            __syncthreads();
        }
    }

    outg[blk * 256 + t] = act;
}

extern "C" void kernel_launch(void* const* d_in, const int* in_sizes, int n_in,
                              void* d_out, int out_size, void* d_ws, size_t ws_size,
                              hipStream_t stream) {
    const float* x = (const float*)d_in[0];
    const float* w = (const float*)d_in[1];
    const float* b = (const float*)d_in[2];
    float* out = (float*)d_out;
    hipLaunchKernelGGL(caps_fused_kernel, dim3(16384), dim3(256), 0, stream,
                       x, w, b, out);
}

// Round 2
// 440.272 us; speedup vs baseline: 1.8479x; 1.8479x over previous
//
#include <hip/hip_runtime.h>
#include <math.h>

// ConvCapsuleLayer fused: 5x5 SAME conv (shared over capsules) + 3-iter routing.
// Each block: one b', one h row, a 1x4 strip of w positions. Grid = 16*32*8 = 4096.
// Per-thread: 2 i's x 4 od channels x 4 positions = 32 fp32 accumulators.
// W is streamed from L2 once per wave per block -> 4x less L2 traffic than
// the 1-position version (26.8 GB -> 6.7 GB).
// Batch scramble (faithful to reference reshape): votes[b',i'] uses
//   i_x = b' >> 1, b_x = ((b'&1)<<3) + i'.

__global__ __launch_bounds__(256, 2) void caps_fused_kernel(
    const float* __restrict__ xg,    // [16,32,32,8,16]
    const float* __restrict__ wg,    // [5,5,16,256] == [400][256] row-major
    const float* __restrict__ bg,    // [256]
    float* __restrict__ outg)        // [16,32,32,16,16]
{
    __shared__ float xs[5 * 8 * 16 * 8];   // [row 5][col 8][c 16][i 8] = 20480 B
    __shared__ float votes_s[4 * 8 * 256]; // [q][i][od] = 32768 B
    __shared__ float act_s[4 * 256];
    __shared__ float logit_s[4 * 128];     // [q][i][o]
    __shared__ float route_s[4 * 128];
    __shared__ float bias_s[256];

    const int t      = threadIdx.x;
    const int blk    = blockIdx.x;
    const int wt     = blk & 7;            // w tile
    const int h0     = (blk >> 3) & 31;
    const int bp     = blk >> 8;           // b'
    const int w0base = wt << 2;
    const int i_x    = bp >> 1;
    const int bbase  = (bp & 1) << 3;

    // ---- stage x window: rows h0-2..h0+2, cols w0base-2..w0base+5, zero-padded
    // idx decode keeps c innermost for coalesced global reads.
    for (int k = 0; k < 20; ++k) {
        int idx = t + (k << 8);            // 0..5119
        int c   = idx & 15;
        int i   = (idx >> 4) & 7;
        int rc  = idx >> 7;                // 0..39
        int cc  = rc & 7;
        int r   = rc >> 3;
        int hh  = h0 + r - 2;
        int ww  = w0base + cc - 2;
        float v = 0.0f;
        if (hh >= 0 && hh < 32 && ww >= 0 && ww < 32) {
            int b_x = bbase + i;
            v = xg[(((b_x * 32 + hh) * 32 + ww) * 8 + i_x) * 16 + c];
        }
        xs[(rc * 16 + c) * 8 + i] = v;
    }
    bias_s[t] = bg[t];
    logit_s[t & 511] = 0.0f;               // t<256 covers first half
    logit_s[256 + t] = 0.0f;
    __syncthreads();

    // ---- conv: wave wv -> i = {2wv, 2wv+1}; lane -> od = lane*4..lane*4+3;
    //            4 positions q in registers.
    const int wv   = t >> 6;
    const int lane = t & 63;

    float acc[2][4][4];                    // [di][comp][q]
    #pragma unroll
    for (int a = 0; a < 2; ++a)
        #pragma unroll
        for (int b = 0; b < 4; ++b)
            #pragma unroll
            for (int q = 0; q < 4; ++q) acc[a][b][q] = 0.0f;

    const float4* w4 = (const float4*)wg;  // [400][64]

    for (int kh = 0; kh < 5; ++kh) {
        for (int kw = 0; kw < 5; ++kw) {
            int wbase = ((kh * 5 + kw) * 16) * 64 + lane;   // float4 idx at c=0
            int xb    = (kh * 8 + kw) * 128 + 2 * wv;       // float idx c=0,q=0
            #pragma unroll 4
            for (int c = 0; c < 16; ++c) {
                float4 wvv = w4[wbase + c * 64];
                #pragma unroll
                for (int q = 0; q < 4; ++q) {
                    float2 xq = *(const float2*)&xs[xb + q * 128 + c * 8];
                    acc[0][0][q] += xq.x * wvv.x;
                    acc[0][1][q] += xq.x * wvv.y;
                    acc[0][2][q] += xq.x * wvv.z;
                    acc[0][3][q] += xq.x * wvv.w;
                    acc[1][0][q] += xq.y * wvv.x;
                    acc[1][1][q] += xq.y * wvv.y;
                    acc[1][2][q] += xq.y * wvv.z;
                    acc[1][3][q] += xq.y * wvv.w;
                }
            }
        }
    }

    // write votes: votes_s[(q*8 + i)*256 + od]
    #pragma unroll
    for (int q = 0; q < 4; ++q) {
        #pragma unroll
        for (int di = 0; di < 2; ++di) {
            float4 v = make_float4(acc[di][0][q], acc[di][1][q],
                                   acc[di][2][q], acc[di][3][q]);
            *(float4*)&votes_s[(q * 8 + 2 * wv + di) * 256 + lane * 4] = v;
        }
    }
    __syncthreads();

    // ---- routing: thread t owns od = t (o = t>>4), vectorized over q.
    const int o = t >> 4;
    float act_r[4];
    for (int it = 0; it < 3; ++it) {
        if (t < 32) {
            int q = t >> 3, i = t & 7;
            const float* lg = &logit_s[q * 128 + i * 16];
            float m = -1e30f;
            #pragma unroll
            for (int oo = 0; oo < 16; ++oo) m = fmaxf(m, lg[oo]);
            float e[16];
            float s = 0.0f;
            #pragma unroll
            for (int oo = 0; oo < 16; ++oo) { e[oo] = __expf(lg[oo] - m); s += e[oo]; }
            float inv = 1.0f / s;
            float* rt = &route_s[q * 128 + i * 16];
            #pragma unroll
            for (int oo = 0; oo < 16; ++oo) rt[oo] = e[oo] * inv;
        }
        __syncthreads();

        #pragma unroll
        for (int q = 0; q < 4; ++q) {
            float pre = bias_s[t];
            #pragma unroll
            for (int i = 0; i < 8; ++i)
                pre += route_s[q * 128 + i * 16 + o] * votes_s[(q * 8 + i) * 256 + t];
            float n2 = pre * pre;
            #pragma unroll
            for (int off = 8; off >= 1; off >>= 1) n2 += __shfl_xor(n2, off, 16);
            act_r[q] = pre * sqrtf(n2) / (1.0f + n2);
        }

        if (it < 2) {
            #pragma unroll
            for (int q = 0; q < 4; ++q) act_s[q * 256 + t] = act_r[q];
            __syncthreads();
            // logits[q][i][o] += sum_d votes[q][i][o*16+d] * act[q][o*16+d]
            #pragma unroll
            for (int rep = 0; rep < 2; ++rep) {
                int j   = t + rep * 256;   // 0..511
                int q   = j >> 7;
                int rem = j & 127;
                int ii  = rem >> 4;
                int oo  = rem & 15;
                float s = 0.0f;
                #pragma unroll
                for (int dd = 0; dd < 16; ++dd)
                    s += votes_s[(q * 8 + ii) * 256 + oo * 16 + dd] *
                         act_s[q * 256 + oo * 16 + dd];
                logit_s[q * 128 + rem] += s;
            }
            __syncthreads();
        }
    }

    // ---- output: [b', h0, w0base+q, o, d]
    #pragma unroll
    for (int q = 0; q < 4; ++q)
        outg[((bp * 32 + h0) * 32 + (w0base + q)) * 256 + t] = act_r[q];
}

extern "C" void kernel_launch(void* const* d_in, const int* in_sizes, int n_in,
                              void* d_out, int out_size, void* d_ws, size_t ws_size,
                              hipStream_t stream) {
    const float* x = (const float*)d_in[0];
    const float* w = (const float*)d_in[1];
    const float* b = (const float*)d_in[2];
    float* out = (float*)d_out;
    hipLaunchKernelGGL(caps_fused_kernel, dim3(4096), dim3(256), 0, stream,
                       x, w, b, out);
}

// Round 3
// 252.490 us; speedup vs baseline: 3.2222x; 1.7437x over previous
//
#include <hip/hip_runtime.h>
#include <math.h>

// ConvCapsuleLayer fused, MFMA split-bf16 edition.
// Conv as GEMM: M=131072 rows (b',i,h,w), K=400 (pad 416), N=256.
// fp32 emulated via hi/lo bf16 split: A*B ~= Ah*Bh + Al*Bh + Ah*Bl  (err ~2^-17).
// Block: one b', one h, 8 w positions -> M_tile=64 (8 i x 8 q). Grid 2048.
// Wave wv owns n in [wv*64, wv*64+64): 4 n-tiles x 4 m-subtiles x f32x4 acc.
// Votes (64x260 fp32) reuse the x-staging LDS region after the conv barrier.
// Batch scramble (faithful to reference reshape): i_x = b'>>1, b_x = ((b'&1)<<3)+i.

typedef __attribute__((ext_vector_type(8))) short short8;
typedef __attribute__((ext_vector_type(4))) float f32x4;

__device__ __forceinline__ void split_bf16(float f, short& hi, short& lo) {
    unsigned u  = __float_as_uint(f);
    unsigned rh = (u + 0x7fffu + ((u >> 16) & 1u)) >> 16;      // RNE to bf16
    hi = (short)rh;
    float l = f - __uint_as_float(rh << 16);
    unsigned ul = __float_as_uint(l);
    unsigned rl = (ul + 0x7fffu + ((ul >> 16) & 1u)) >> 16;
    lo = (short)rl;
}

// W [400][256] fp32 -> Bh/Bl [52 kgroups][256 n][8 k] bf16, k padded 400->416 with 0.
__global__ void prep_w(const float* __restrict__ wg,
                       short* __restrict__ bh, short* __restrict__ bl) {
    int k = blockIdx.x;        // 0..415
    int n = threadIdx.x;       // 0..255
    float f = (k < 400) ? wg[k * 256 + n] : 0.0f;
    short h, l;
    split_bf16(f, h, l);
    int dst = (k >> 3) * 2048 + n * 8 + (k & 7);
    bh[dst] = h;
    bl[dst] = l;
}

#define VSTRIDE 260

__global__ __launch_bounds__(256, 2) void caps_mfma_kernel(
    const float* __restrict__ xg,     // [16,32,32,8,16]
    const short* __restrict__ bhg,    // [52][256][8]
    const short* __restrict__ blg,
    const float* __restrict__ bg,     // [256]
    float* __restrict__ outg)         // [16,32,32,16,16]
{
    __shared__ char  buf[VSTRIDE * 64 * 4];   // 66560 B: xs (31232) then votes
    __shared__ float logit_s[1024];           // [q8][i8][o16]
    __shared__ float route_s[1024];
    __shared__ float bias_s[256];

    short* xs_h    = (short*)buf;             // [i8][rc 60][c16] + 16 pad per i
    short* xs_l    = (short*)(buf + 15616);
    float* votes_s = (float*)buf;             // [r64][260]  (r = q*8+i)

    const int t      = threadIdx.x;
    const int blk    = blockIdx.x;            // 2048
    const int wt     = blk & 3;
    const int h0     = (blk >> 2) & 31;
    const int bp     = blk >> 7;
    const int w0base = wt << 3;
    const int i_x    = bp >> 1;
    const int bbase  = (bp & 1) << 3;

    // ---- stage x window (5 rows x 12 cols x 16 c x 8 i), split to bf16 hi/lo
    #pragma unroll
    for (int it = 0; it < 30; ++it) {
        int idx  = t + (it << 8);
        int c    = idx & 15;
        int rest = idx >> 4;
        int i    = rest & 7;
        int rc   = rest >> 3;                 // 0..59 = kh*12 + ww
        int r    = rc / 12;
        int cc   = rc - r * 12;
        int hh   = h0 + r - 2;
        int ww   = w0base + cc - 2;
        float f  = 0.0f;
        if (hh >= 0 && hh < 32 && ww >= 0 && ww < 32)
            f = xg[((((bbase + i) * 32 + hh) * 32 + ww) * 8 + i_x) * 16 + c];
        short h, l;
        split_bf16(f, h, l);
        int a = i * 976 + rc * 16 + c;
        xs_h[a] = h;
        xs_l[a] = l;
    }
    bias_s[t] = bg[t];
    logit_s[t] = 0.f; logit_s[t + 256] = 0.f; logit_s[t + 512] = 0.f; logit_s[t + 768] = 0.f;
    __syncthreads();

    // ---- MFMA conv
    const int wv   = t >> 6;
    const int lane = t & 63;
    const int lrow = lane & 15;     // m (and n) index within 16-tile
    const int h8   = lane >> 4;     // k-half 0..3
    const int ia   = lrow & 7;      // i of this A row
    const int qh   = lrow >> 3;     // q parity

    f32x4 acc[4][4];
    #pragma unroll
    for (int ms = 0; ms < 4; ++ms)
        #pragma unroll
        for (int nt = 0; nt < 4; ++nt)
            acc[ms][nt] = (f32x4){0.f, 0.f, 0.f, 0.f};

    const short8* bhp = (const short8*)bhg;   // [52][256] short8
    const short8* blp = (const short8*)blg;

    for (int chunk = 0; chunk < 13; ++chunk) {
        int k  = chunk * 32 + h8 * 8;
        bool valid = (k < 400);
        int p  = k >> 4;
        int kh = p / 5;
        int kw = p - kh * 5;
        int c0 = k & 15;                       // 0 or 8
        int abase = ia * 976 + (kh * 12 + kw + qh) * 16 + c0;

        short8 ah[4], al[4];
        #pragma unroll
        for (int ms = 0; ms < 4; ++ms) {
            int a = abase + ms * 32;           // q = ms*2 + qh  -> +32 elems per ms
            if (valid) {
                ah[ms] = *(const short8*)&xs_h[a];
                al[ms] = *(const short8*)&xs_l[a];
            } else {
                ah[ms] = (short8)0;
                al[ms] = (short8)0;
            }
        }
        int g = chunk * 4 + h8;                // kgroup 0..51
        short8 bh[4], bl[4];
        #pragma unroll
        for (int nt = 0; nt < 4; ++nt) {
            int n = wv * 64 + nt * 16 + lrow;
            bh[nt] = bhp[g * 256 + n];
            bl[nt] = blp[g * 256 + n];
        }
        #pragma unroll
        for (int ms = 0; ms < 4; ++ms)
            #pragma unroll
            for (int nt = 0; nt < 4; ++nt) {
                acc[ms][nt] = __builtin_amdgcn_mfma_f32_16x16x32_bf16(ah[ms], bh[nt], acc[ms][nt], 0, 0, 0);
                acc[ms][nt] = __builtin_amdgcn_mfma_f32_16x16x32_bf16(al[ms], bh[nt], acc[ms][nt], 0, 0, 0);
                acc[ms][nt] = __builtin_amdgcn_mfma_f32_16x16x32_bf16(ah[ms], bl[nt], acc[ms][nt], 0, 0, 0);
            }
    }

    __syncthreads();   // xs region dead; reuse as votes

    // votes_s[r][n]: r = ms*16 + h8*4 + reg (= q*8+i), n = wv*64 + nt*16 + lrow
    #pragma unroll
    for (int ms = 0; ms < 4; ++ms)
        #pragma unroll
        for (int nt = 0; nt < 4; ++nt)
            #pragma unroll
            for (int reg = 0; reg < 4; ++reg)
                votes_s[(ms * 16 + h8 * 4 + reg) * VSTRIDE + wv * 64 + nt * 16 + lrow] =
                    acc[ms][nt][reg];
    __syncthreads();

    // ---- routing: thread t owns od = t (o = t>>4, d = t&15), loops q = 0..7
    const int o = t >> 4;
    const int d = t & 15;
    float act_r[8];
    for (int it = 0; it < 3; ++it) {
        if (t < 64) {                          // softmax over o for each (q,i)
            const float* lg = &logit_s[t * 16];
            float m = -1e30f;
            #pragma unroll
            for (int oo = 0; oo < 16; ++oo) m = fmaxf(m, lg[oo]);
            float e[16];
            float s = 0.0f;
            #pragma unroll
            for (int oo = 0; oo < 16; ++oo) { e[oo] = __expf(lg[oo] - m); s += e[oo]; }
            float inv = 1.0f / s;
            float* rt = &route_s[t * 16];
            #pragma unroll
            for (int oo = 0; oo < 16; ++oo) rt[oo] = e[oo] * inv;
        }
        __syncthreads();

        #pragma unroll
        for (int q = 0; q < 8; ++q) {
            float v[8];
            float pre = bias_s[t];
            #pragma unroll
            for (int i = 0; i < 8; ++i) {
                v[i] = votes_s[(q * 8 + i) * VSTRIDE + t];
                pre += route_s[q * 128 + i * 16 + o] * v[i];
            }
            float n2 = pre * pre;
            #pragma unroll
            for (int off = 8; off >= 1; off >>= 1) n2 += __shfl_xor(n2, off, 16);
            float act = pre * sqrtf(n2) / (1.0f + n2);
            act_r[q] = act;

            if (it < 2) {
                #pragma unroll
                for (int i = 0; i < 8; ++i) {
                    float prod = v[i] * act;
                    #pragma unroll
                    for (int off = 8; off >= 1; off >>= 1) prod += __shfl_xor(prod, off, 16);
                    if (d == i) logit_s[q * 128 + i * 16 + o] += prod;
                }
            }
        }
        if (it < 2) __syncthreads();
    }

    // ---- output [b',h0,w0base+q,o,d]
    #pragma unroll
    for (int q = 0; q < 8; ++q)
        outg[((bp * 32 + h0) * 32 + (w0base + q)) * 256 + t] = act_r[q];
}

extern "C" void kernel_launch(void* const* d_in, const int* in_sizes, int n_in,
                              void* d_out, int out_size, void* d_ws, size_t ws_size,
                              hipStream_t stream) {
    const float* x = (const float*)d_in[0];
    const float* w = (const float*)d_in[1];
    const float* b = (const float*)d_in[2];
    float* out = (float*)d_out;

    short* bh = (short*)d_ws;                          // 52*256*8*2 = 212992 B
    short* bl = (short*)((char*)d_ws + 52 * 256 * 8 * 2);

    hipLaunchKernelGGL(prep_w, dim3(416), dim3(256), 0, stream, w, bh, bl);
    hipLaunchKernelGGL(caps_mfma_kernel, dim3(2048), dim3(256), 0, stream,
                       x, bh, bl, b, out);
}

// Round 4
// 162.426 us; speedup vs baseline: 5.0088x; 1.5545x over previous
//
#include <hip/hip_runtime.h>
#include <math.h>

// ConvCapsuleLayer fused, MFMA split-bf16, register-resident routing.
// Conv as GEMM: M=131072 rows (b',i,h,w), K=400 (pad 416), N=256.
// fp32 emulated via hi/lo bf16 split: A*B ~= Ah*Bh + Al*Bh + Ah*Bl (err ~2^-17).
// Block: one b', one h, 8 w positions -> M_tile=64 (8 i x 8 q). Grid 2048.
// After conv, votes are transposed acc-layout -> od-layout through a HALF-size
// LDS buffer (2 passes, 33.3 KB reusing the xs region) into 64 regs/thread;
// routing (3 iters) runs from registers. LDS 41.5 KB -> 3 blocks/CU.
// Batch scramble (faithful to reference reshape): i_x = b'>>1, b_x=((b'&1)<<3)+i.

typedef __attribute__((ext_vector_type(8))) short short8;
typedef __attribute__((ext_vector_type(4))) float f32x4;

__device__ __forceinline__ void split_bf16(float f, short& hi, short& lo) {
    unsigned u  = __float_as_uint(f);
    unsigned rh = (u + 0x7fffu + ((u >> 16) & 1u)) >> 16;      // RNE to bf16
    hi = (short)rh;
    float l = f - __uint_as_float(rh << 16);
    unsigned ul = __float_as_uint(l);
    unsigned rl = (ul + 0x7fffu + ((ul >> 16) & 1u)) >> 16;
    lo = (short)rl;
}

// W [400][256] fp32 -> Bh/Bl [52 kgroups][256 n][8 k] bf16, k padded 400->416.
__global__ void prep_w(const float* __restrict__ wg,
                       short* __restrict__ bh, short* __restrict__ bl) {
    int k = blockIdx.x;        // 0..415
    int n = threadIdx.x;       // 0..255
    float f = (k < 400) ? wg[k * 256 + n] : 0.0f;
    short h, l;
    split_bf16(f, h, l);
    int dst = (k >> 3) * 2048 + n * 8 + (k & 7);
    bh[dst] = h;
    bl[dst] = l;
}

#define VSTRIDE 260

__global__ __launch_bounds__(256, 3) void caps_mfma_kernel(
    const float* __restrict__ xg,     // [16,32,32,8,16]
    const short* __restrict__ bhg,    // [52][256][8]
    const short* __restrict__ blg,
    const float* __restrict__ bg,     // [256]
    float* __restrict__ outg)         // [16,32,32,16,16]
{
    __shared__ __align__(16) char buf[VSTRIDE * 32 * 4];  // 33280 B: xs / half-votes
    __shared__ float logit_s[1024];           // [q8][i8][o16]
    __shared__ float route_s[1024];           // [q8][o16][i8]  (transposed!)

    short* xs_h    = (short*)buf;             // [i8][rc 60][c16] (+16 pad per i)
    short* xs_l    = (short*)(buf + 15616);
    float* votes_s = (float*)buf;             // [r32][260] per pass

    const int t      = threadIdx.x;
    const int blk    = blockIdx.x;            // 2048
    const int wt     = blk & 3;
    const int h0     = (blk >> 2) & 31;
    const int bp     = blk >> 7;
    const int w0base = wt << 3;
    const int i_x    = bp >> 1;
    const int bbase  = (bp & 1) << 3;

    const float bias_r = bg[t];

    // ---- stage x window (5 rows x 12 cols x 16 c x 8 i), split to bf16 hi/lo
    #pragma unroll
    for (int it = 0; it < 30; ++it) {
        int idx  = t + (it << 8);
        int c    = idx & 15;
        int rest = idx >> 4;
        int i    = rest & 7;
        int rc   = rest >> 3;                 // 0..59 = kh*12 + ww
        int r    = rc / 12;
        int cc   = rc - r * 12;
        int hh   = h0 + r - 2;
        int ww   = w0base + cc - 2;
        float f  = 0.0f;
        if (hh >= 0 && hh < 32 && ww >= 0 && ww < 32)
            f = xg[((((bbase + i) * 32 + hh) * 32 + ww) * 8 + i_x) * 16 + c];
        short h, l;
        split_bf16(f, h, l);
        int a = i * 976 + rc * 16 + c;
        xs_h[a] = h;
        xs_l[a] = l;
    }
    __syncthreads();

    // ---- MFMA conv
    const int wv   = t >> 6;
    const int lane = t & 63;
    const int lrow = lane & 15;     // m (and n) index within 16-tile
    const int h8   = lane >> 4;     // k-quarter 0..3
    const int ia   = lrow & 7;      // i of this A row
    const int qh   = lrow >> 3;     // q parity

    f32x4 acc[4][4];
    #pragma unroll
    for (int ms = 0; ms < 4; ++ms)
        #pragma unroll
        for (int nt = 0; nt < 4; ++nt)
            acc[ms][nt] = (f32x4){0.f, 0.f, 0.f, 0.f};

    const short8* bhp = (const short8*)bhg;   // [52][256] short8
    const short8* blp = (const short8*)blg;

    for (int chunk = 0; chunk < 13; ++chunk) {
        int k  = chunk * 32 + h8 * 8;
        bool valid = (k < 400);
        int p  = k >> 4;
        int kh = p / 5;
        int kw = p - kh * 5;
        int c0 = k & 15;                       // 0 or 8
        int abase = ia * 976 + (kh * 12 + kw + qh) * 16 + c0;

        int g = chunk * 4 + h8;                // kgroup 0..51
        short8 bh[4], bl[4];
        #pragma unroll
        for (int nt = 0; nt < 4; ++nt) {
            int n = wv * 64 + nt * 16 + lrow;
            bh[nt] = bhp[g * 256 + n];
            bl[nt] = blp[g * 256 + n];
        }
        short8 ah[4], al[4];
        #pragma unroll
        for (int ms = 0; ms < 4; ++ms) {
            int a = abase + ms * 32;           // q = ms*2 + qh
            if (valid) {
                ah[ms] = *(const short8*)&xs_h[a];
                al[ms] = *(const short8*)&xs_l[a];
            } else {
                ah[ms] = (short8)0;
                al[ms] = (short8)0;
            }
        }
        #pragma unroll
        for (int ms = 0; ms < 4; ++ms)
            #pragma unroll
            for (int nt = 0; nt < 4; ++nt) {
                acc[ms][nt] = __builtin_amdgcn_mfma_f32_16x16x32_bf16(ah[ms], bh[nt], acc[ms][nt], 0, 0, 0);
                acc[ms][nt] = __builtin_amdgcn_mfma_f32_16x16x32_bf16(al[ms], bh[nt], acc[ms][nt], 0, 0, 0);
                acc[ms][nt] = __builtin_amdgcn_mfma_f32_16x16x32_bf16(ah[ms], bl[nt], acc[ms][nt], 0, 0, 0);
            }
    }

    __syncthreads();   // xs region dead; reuse as half-votes buffer

    // ---- transpose acc -> v[q][i] regs, two half-passes (rows 0..31, 32..63)
    float v[8][8];
    #pragma unroll
    for (int pass = 0; pass < 2; ++pass) {
        #pragma unroll
        for (int ms = 0; ms < 2; ++ms)
            #pragma unroll
            for (int nt = 0; nt < 4; ++nt)
                #pragma unroll
                for (int reg = 0; reg < 4; ++reg)
                    votes_s[(ms * 16 + h8 * 4 + reg) * VSTRIDE + wv * 64 + nt * 16 + lrow] =
                        acc[pass * 2 + ms][nt][reg];
        __syncthreads();
        #pragma unroll
        for (int q = 0; q < 4; ++q)
            #pragma unroll
            for (int i = 0; i < 8; ++i)
                v[pass * 4 + q][i] = votes_s[(q * 8 + i) * VSTRIDE + t];
        __syncthreads();
    }

    // ---- routing from registers: thread t owns od=t (o=t>>4, d=t&15), q-loop.
    const int o = t >> 4;
    const int d = t & 15;
    const bool b3 = d & 8, b2 = d & 4, b1 = d & 2;
    const int i_mine = (d >> 1) & 7;
    float act_r[8];

    // ---- it = 0: route == 1/16 exactly (softmax of zeros); logits '=' write.
    #pragma unroll
    for (int q = 0; q < 8; ++q) {
        float s = 0.0f;
        #pragma unroll
        for (int i = 0; i < 8; ++i) s += v[q][i];
        float pre = bias_r + 0.0625f * s;
        float n2 = pre * pre;
        #pragma unroll
        for (int off = 8; off >= 1; off >>= 1) n2 += __shfl_xor(n2, off, 16);
        float act = pre * sqrtf(n2) / (1.0f + n2);
        act_r[q] = act;

        // agreement: 8 dot-sums over 16 lanes via reduce-scatter butterfly
        float p[8];
        #pragma unroll
        for (int i = 0; i < 8; ++i) p[i] = v[q][i] * act;
        float s4[4];
        #pragma unroll
        for (int j = 0; j < 4; ++j) {
            float send = b3 ? p[j] : p[j + 4];
            float r = __shfl_xor(send, 8, 16);
            s4[j] = (b3 ? p[j + 4] : p[j]) + r;
        }
        float s2[2];
        #pragma unroll
        for (int j = 0; j < 2; ++j) {
            float send = b2 ? s2[0] * 0.f + s4[j] : s4[j + 2];   // see note below
            // (rewritten cleanly)
            send = b2 ? s4[j] : s4[j + 2];
            float r = __shfl_xor(send, 4, 16);
            s2[j] = (b2 ? s4[j + 2] : s4[j]) + r;
        }
        float send1 = b1 ? s2[0] : s2[1];
        float r1 = __shfl_xor(send1, 2, 16);
        float s1 = (b1 ? s2[1] : s2[0]) + r1;
        float L = s1 + __shfl_xor(s1, 1, 16);
        if (!(d & 1)) logit_s[q * 128 + i_mine * 16 + o] = L;
    }
    __syncthreads();

    // ---- it = 1, 2
    #pragma unroll
    for (int it = 1; it < 3; ++it) {
        if (t < 64) {                          // softmax over o for each (q,i)
            int q = t >> 3, i = t & 7;
            const float* lg = &logit_s[t * 16];
            float m = -1e30f;
            #pragma unroll
            for (int oo = 0; oo < 16; ++oo) m = fmaxf(m, lg[oo]);
            float e[16];
            float s = 0.0f;
            #pragma unroll
            for (int oo = 0; oo < 16; ++oo) { e[oo] = __expf(lg[oo] - m); s += e[oo]; }
            float inv = 1.0f / s;
            #pragma unroll
            for (int oo = 0; oo < 16; ++oo) route_s[q * 128 + oo * 8 + i] = e[oo] * inv;
        }
        __syncthreads();

        #pragma unroll
        for (int q = 0; q < 8; ++q) {
            const float4* rp = (const float4*)&route_s[q * 128 + o * 8];
            float4 ra = rp[0], rb = rp[1];
            float pre = bias_r
                + ra.x * v[q][0] + ra.y * v[q][1] + ra.z * v[q][2] + ra.w * v[q][3]
                + rb.x * v[q][4] + rb.y * v[q][5] + rb.z * v[q][6] + rb.w * v[q][7];
            float n2 = pre * pre;
            #pragma unroll
            for (int off = 8; off >= 1; off >>= 1) n2 += __shfl_xor(n2, off, 16);
            float act = pre * sqrtf(n2) / (1.0f + n2);
            act_r[q] = act;

            if (it < 2) {
                float p[8];
                #pragma unroll
                for (int i = 0; i < 8; ++i) p[i] = v[q][i] * act;
                float s4[4];
                #pragma unroll
                for (int j = 0; j < 4; ++j) {
                    float send = b3 ? p[j] : p[j + 4];
                    float r = __shfl_xor(send, 8, 16);
                    s4[j] = (b3 ? p[j + 4] : p[j]) + r;
                }
                float s2[2];
                #pragma unroll
                for (int j = 0; j < 2; ++j) {
                    float send = b2 ? s4[j] : s4[j + 2];
                    float r = __shfl_xor(send, 4, 16);
                    s2[j] = (b2 ? s4[j + 2] : s4[j]) + r;
                }
                float send1 = b1 ? s2[0] : s2[1];
                float r1 = __shfl_xor(send1, 2, 16);
                float s1 = (b1 ? s2[1] : s2[0]) + r1;
                float L = s1 + __shfl_xor(s1, 1, 16);
                if (!(d & 1)) logit_s[q * 128 + i_mine * 16 + o] += L;
            }
        }
        if (it < 2) __syncthreads();
    }

    // ---- output [b',h0,w0base+q,o,d]
    #pragma unroll
    for (int q = 0; q < 8; ++q)
        outg[((bp * 32 + h0) * 32 + (w0base + q)) * 256 + t] = act_r[q];
}

extern "C" void kernel_launch(void* const* d_in, const int* in_sizes, int n_in,
                              void* d_out, int out_size, void* d_ws, size_t ws_size,
                              hipStream_t stream) {
    const float* x = (const float*)d_in[0];
    const float* w = (const float*)d_in[1];
    const float* b = (const float*)d_in[2];
    float* out = (float*)d_out;

    short* bh = (short*)d_ws;                          // 52*256*8*2 = 212992 B
    short* bl = (short*)((char*)d_ws + 52 * 256 * 8 * 2);

    hipLaunchKernelGGL(prep_w, dim3(416), dim3(256), 0, stream, w, bh, bl);
    hipLaunchKernelGGL(caps_mfma_kernel, dim3(2048), dim3(256), 0, stream,
                       x, bh, bl, b, out);
}

// Round 6
// 141.510 us; speedup vs baseline: 5.7492x; 1.1478x over previous
//
#include <hip/hip_runtime.h>
#include <math.h>

// ConvCapsuleLayer fused: MFMA split-bf16 conv + register-resident routing.
// This round: DS-pipe diet — DPP cross-lane reductions (VALU instead of LDS),
// b128 xor-swizzled vote transpose, float4/b64 staging, peeled tail chunk,
// parallel softmax. Arithmetic identical to round 4 (absmax ~4e-3).
// Batch scramble (faithful to reference reshape): i_x = b'>>1, b_x=((b'&1)<<3)+i.

typedef __attribute__((ext_vector_type(8))) short short8;
typedef __attribute__((ext_vector_type(4))) short short4v;
typedef __attribute__((ext_vector_type(4))) float f32x4;

__device__ __forceinline__ void split_bf16(float f, short& hi, short& lo) {
    unsigned u  = __float_as_uint(f);
    unsigned rh = (u + 0x7fffu + ((u >> 16) & 1u)) >> 16;      // RNE to bf16
    hi = (short)rh;
    float l = f - __uint_as_float(rh << 16);
    unsigned ul = __float_as_uint(l);
    unsigned rl = (ul + 0x7fffu + ((ul >> 16) & 1u)) >> 16;
    lo = (short)rl;
}

// W [400][256] fp32 -> Bh/Bl [52 kgroups][256 n][8 k] bf16, k padded 400->416.
__global__ void prep_w(const float* __restrict__ wg,
                       short* __restrict__ bh, short* __restrict__ bl) {
    int k = blockIdx.x;        // 0..415
    int n = threadIdx.x;       // 0..255
    float f = (k < 400) ? wg[k * 256 + n] : 0.0f;
    short h, l;
    split_bf16(f, h, l);
    int dst = (k >> 3) * 2048 + n * 8 + (k & 7);
    bh[dst] = h;
    bl[dst] = l;
}

// DPP helpers: row = 16 lanes on CDNA. 0xB1 = quad_perm xor1, 0x4E = xor2,
// 0x124 = row_ror:4, 0x128 = row_ror:8 (ror8 == xor8 on a 16-ring).
template<int CTRL>
__device__ __forceinline__ float dppf(float x) {
    return __int_as_float(__builtin_amdgcn_update_dpp(
        0, __float_as_int(x), CTRL, 0xF, 0xF, true));
}
__device__ __forceinline__ float sum16(float x) {
    x += dppf<0xB1>(x);    // pair sums
    x += dppf<0x4E>(x);    // quad sums (quad-uniform now)
    x += dppf<0x124>(x);   // + neighbor quad
    x += dppf<0x128>(x);   // + remaining two quads
    return x;
}

__global__ __launch_bounds__(256, 3) void caps_mfma_kernel(
    const float* __restrict__ xg,     // [16,32,32,8,16]
    const short* __restrict__ bhg,    // [52][256][8]
    const short* __restrict__ blg,
    const float* __restrict__ bg,     // [256]
    float* __restrict__ outg)         // [16,32,32,16,16]
{
    __shared__ __align__(16) char buf[32768];  // xs (31232 B) / swizzled votes
    __shared__ float logit_s[1024];            // [q8][i8][o16]
    __shared__ float route_s[1024];            // [q8][o16][i8] (transposed)

    short* xs_h = (short*)buf;                 // [i8][rc 60][c16] (+pad)
    short* xs_l = (short*)(buf + 15616);
    float* vt   = (float*)buf;                 // votes^T [n256][r32], swizzled

    const int t      = threadIdx.x;
    const int blk    = blockIdx.x;             // 2048
    const int wt     = blk & 3;
    const int h0     = (blk >> 2) & 31;
    const int bp     = blk >> 7;
    const int w0base = wt << 3;
    const int i_x    = bp >> 1;
    const int bbase  = (bp & 1) << 3;

    const float bias_r = bg[t];

    // ---- stage x window (60 rc x 16 c x 8 i = 7680 floats) as 1920 float4
    const float4* x4 = (const float4*)xg;
    #pragma unroll
    for (int kk = 0; kk < 8; ++kk) {
        int idx4 = t + (kk << 8);
        if (idx4 < 1920) {
            int c2 = idx4 & 3;                 // c = c2*4
            int i  = (idx4 >> 2) & 7;
            int rc = idx4 >> 5;                // 0..59 = r*12 + cc
            int r  = rc / 12;
            int cc = rc - r * 12;
            int hh = h0 + r - 2;
            int ww = w0base + cc - 2;
            float4 f = make_float4(0.f, 0.f, 0.f, 0.f);
            if (hh >= 0 && hh < 32 && ww >= 0 && ww < 32)
                f = x4[((((bbase + i) * 32 + hh) * 32 + ww) * 8 + i_x) * 4 + c2];
            short hx, lx, hy, ly, hz, lz, hw, lw;
            split_bf16(f.x, hx, lx);
            split_bf16(f.y, hy, ly);
            split_bf16(f.z, hz, lz);
            split_bf16(f.w, hw, lw);
            short4v h4, l4;
            h4.x = hx; h4.y = hy; h4.z = hz; h4.w = hw;
            l4.x = lx; l4.y = ly; l4.z = lz; l4.w = lw;
            int a = i * 976 + rc * 16 + c2 * 4;
            *(short4v*)&xs_h[a] = h4;
            *(short4v*)&xs_l[a] = l4;
        }
    }
    __syncthreads();

    // ---- MFMA conv
    const int wv   = t >> 6;
    const int lane = t & 63;
    const int lrow = lane & 15;     // m (and n) index within 16-tile
    const int h8   = lane >> 4;     // k-quarter 0..3
    const int ia   = lrow & 7;      // i of this A row
    const int qh   = lrow >> 3;     // q parity

    f32x4 acc[4][4];
    #pragma unroll
    for (int ms = 0; ms < 4; ++ms)
        #pragma unroll
        for (int nt = 0; nt < 4; ++nt)
            acc[ms][nt] = (f32x4){0.f, 0.f, 0.f, 0.f};

    const short8* bhp = (const short8*)bhg;   // [52][256] short8
    const short8* blp = (const short8*)blg;

#define CONV_CHUNK(CH, TAIL)                                                   \
    {                                                                          \
        int k  = (CH) * 32 + h8 * 8;                                           \
        int p  = k >> 4;                                                       \
        int kh = p / 5;                                                        \
        int kw = p - kh * 5;                                                   \
        int c0 = k & 15;                                                       \
        int abase = ia * 976 + (kh * 12 + kw + qh) * 16 + c0;                  \
        int g = (CH) * 4 + h8;                                                 \
        short8 bhv[4], blv[4];                                                 \
        _Pragma("unroll")                                                      \
        for (int nt = 0; nt < 4; ++nt) {                                       \
            int n = wv * 64 + nt * 16 + lrow;                                  \
            bhv[nt] = bhp[g * 256 + n];                                        \
            blv[nt] = blp[g * 256 + n];                                        \
        }                                                                      \
        _Pragma("unroll")                                                      \
        for (int ms = 0; ms < 4; ++ms) {                                       \
            short8 ahv, alv;                                                   \
            if (!(TAIL) || h8 < 2) {                                           \
                ahv = *(const short8*)&xs_h[abase + ms * 32];                  \
                alv = *(const short8*)&xs_l[abase + ms * 32];                  \
            } else { ahv = (short8)0; alv = (short8)0; }                       \
            _Pragma("unroll")                                                  \
            for (int nt = 0; nt < 4; ++nt) {                                   \
                acc[ms][nt] = __builtin_amdgcn_mfma_f32_16x16x32_bf16(ahv, bhv[nt], acc[ms][nt], 0, 0, 0); \
                acc[ms][nt] = __builtin_amdgcn_mfma_f32_16x16x32_bf16(alv, bhv[nt], acc[ms][nt], 0, 0, 0); \
                acc[ms][nt] = __builtin_amdgcn_mfma_f32_16x16x32_bf16(ahv, blv[nt], acc[ms][nt], 0, 0, 0); \
            }                                                                  \
        }                                                                      \
    }

    for (int ch = 0; ch < 12; ++ch) CONV_CHUNK(ch, false)
    CONV_CHUNK(12, true)
#undef CONV_CHUNK

    // ---- transpose acc -> v[q][i] regs via swizzled column-major votes^T.
    // vt dword addr = n*32 + ((rb ^ (n&7))<<2), rb = r>>2. b128, bank-balanced.
    float v[8][8];
    #pragma unroll
    for (int pass = 0; pass < 2; ++pass) {
        __syncthreads();                       // xs / previous-pass reads done
        #pragma unroll
        for (int msp = 0; msp < 2; ++msp) {
            int rb = msp * 4 + h8;
            #pragma unroll
            for (int nt = 0; nt < 4; ++nt) {
                int n = wv * 64 + nt * 16 + lrow;
                *(f32x4*)&vt[n * 32 + ((rb ^ (n & 7)) << 2)] =
                    acc[pass * 2 + msp][nt];
            }
        }
        __syncthreads();
        #pragma unroll
        for (int rb = 0; rb < 8; ++rb) {
            f32x4 x = *(const f32x4*)&vt[t * 32 + ((rb ^ (t & 7)) << 2)];
            int q = pass * 4 + (rb >> 1);
            int ib = (rb & 1) * 4;
            v[q][ib + 0] = x[0];
            v[q][ib + 1] = x[1];
            v[q][ib + 2] = x[2];
            v[q][ib + 3] = x[3];
        }
    }

    // ---- routing from registers: thread t owns od=t (o=t>>4, d=t&15).
    const int o = t >> 4;
    const int d = t & 15;
    const bool b8  = (d & 8) != 0;
    const bool b2v = (d & 2) != 0;
    const bool b1v = (d & 1) != 0;
    const int  im  = (b8 ? 4 : 0) + (b2v ? 2 : 0) + (b1v ? 1 : 0);
    const bool wr  = (d & 4) == 0;
    float act_r[8];

    // agreement: 8 dot-sums over 16 lanes; DPP reduce-scatter, one ds_swizzle
    auto agree = [&](const float* vq, float act, int q, bool first) {
        float p[8];
        #pragma unroll
        for (int i = 0; i < 8; ++i) p[i] = vq[i] * act;
        float s4[4];
        #pragma unroll
        for (int j = 0; j < 4; ++j) {          // exchange lane^8 (ror8)
            float send = b8 ? p[j] : p[j + 4];
            float rcv  = dppf<0x128>(send);
            s4[j] = (b8 ? p[j + 4] : p[j]) + rcv;
        }
        float s2[2];
        #pragma unroll
        for (int j = 0; j < 2; ++j) {          // exchange lane^2
            float send = b2v ? s4[j] : s4[j + 2];
            float rcv  = dppf<0x4E>(send);
            s2[j] = (b2v ? s4[j + 2] : s4[j]) + rcv;
        }
        float send = b1v ? s2[0] : s2[1];      // exchange lane^1
        float rcv  = dppf<0xB1>(send);
        float s1 = (b1v ? s2[1] : s2[0]) + rcv;
        // final: exchange lane^4 (the one non-DPP involution) via ds_swizzle
        float L = s1 + __int_as_float(
            __builtin_amdgcn_ds_swizzle(__float_as_int(s1), 0x101F));
        if (wr) {
            float* dst = &logit_s[q * 128 + im * 16 + o];
            if (first) *dst = L; else *dst += L;
        }
    };

    // ---- it = 0: route == 1/16 exactly; logits written with '=' (no init).
    #pragma unroll
    for (int q = 0; q < 8; ++q) {
        float s = 0.0f;
        #pragma unroll
        for (int i = 0; i < 8; ++i) s += v[q][i];
        float pre = bias_r + 0.0625f * s;
        float n2 = sum16(pre * pre);
        float act = pre * sqrtf(n2) * __builtin_amdgcn_rcpf(1.0f + n2);
        act_r[q] = act;
        agree(v[q], act, q, true);
    }
    __syncthreads();

    // ---- it = 1, 2
    #pragma unroll
    for (int it = 1; it < 3; ++it) {
        {   // parallel softmax: thread -> (row r = q*8+i) = t>>2, 4 o's = (t&3)*4..
            int rr = t >> 2, sq = rr >> 3, si = rr & 7, sj = t & 3;
            f32x4 lg = *(const f32x4*)&logit_s[rr * 16 + sj * 4];
            float m = fmaxf(fmaxf(lg[0], lg[1]), fmaxf(lg[2], lg[3]));
            m = fmaxf(m, dppf<0xB1>(m));       // quad max (4 lanes = same row)
            m = fmaxf(m, dppf<0x4E>(m));
            float e0 = __expf(lg[0] - m), e1 = __expf(lg[1] - m);
            float e2 = __expf(lg[2] - m), e3 = __expf(lg[3] - m);
            float ss = e0 + e1 + e2 + e3;
            ss += dppf<0xB1>(ss);
            ss += dppf<0x4E>(ss);
            float inv = __builtin_amdgcn_rcpf(ss);
            float* rt = &route_s[sq * 128 + si];
            rt[(sj * 4 + 0) * 8] = e0 * inv;
            rt[(sj * 4 + 1) * 8] = e1 * inv;
            rt[(sj * 4 + 2) * 8] = e2 * inv;
            rt[(sj * 4 + 3) * 8] = e3 * inv;
        }
        __syncthreads();

        #pragma unroll
        for (int q = 0; q < 8; ++q) {
            const f32x4* rp = (const f32x4*)&route_s[q * 128 + o * 8];
            f32x4 ra = rp[0], rb2 = rp[1];
            float pre = bias_r
                + ra[0] * v[q][0] + ra[1] * v[q][1] + ra[2] * v[q][2] + ra[3] * v[q][3]
                + rb2[0] * v[q][4] + rb2[1] * v[q][5] + rb2[2] * v[q][6] + rb2[3] * v[q][7];
            float n2 = sum16(pre * pre);
            float act = pre * sqrtf(n2) * __builtin_amdgcn_rcpf(1.0f + n2);
            act_r[q] = act;
            if (it == 1) agree(v[q], act, q, false);
        }
        if (it == 1) __syncthreads();
    }

    // ---- output [b',h0,w0base+q,o,d]
    #pragma unroll
    for (int q = 0; q < 8; ++q)
        outg[((bp * 32 + h0) * 32 + (w0base + q)) * 256 + t] = act_r[q];
}

extern "C" void kernel_launch(void* const* d_in, const int* in_sizes, int n_in,
                              void* d_out, int out_size, void* d_ws, size_t ws_size,
                              hipStream_t stream) {
    const float* x = (const float*)d_in[0];
    const float* w = (const float*)d_in[1];
    const float* b = (const float*)d_in[2];
    float* out = (float*)d_out;

    short* bh = (short*)d_ws;                          // 52*256*8*2 = 212992 B
    short* bl = (short*)((char*)d_ws + 52 * 256 * 8 * 2);

    hipLaunchKernelGGL(prep_w, dim3(416), dim3(256), 0, stream, w, bh, bl);
    hipLaunchKernelGGL(caps_mfma_kernel, dim3(2048), dim3(256), 0, stream,
                       x, bh, bl, b, out);
}

// Round 7
// 122.508 us; speedup vs baseline: 6.6409x; 1.1551x over previous
//
#include <hip/hip_runtime.h>
#include <math.h>

// ConvCapsuleLayer fused: MFMA 2-term fp16 conv + register-resident routing.
// Conv as GEMM: M=131072 (b',i,h,w), K=400(pad 416), N=256.
// fp32 emulated: A split exactly as fp16 hi+lo (Ah+Al ~= x to 2^-21),
// B = fp16(W) single -> votes = Ah*Bh + Al*Bh = x * fp16(W).
// Vote err ~1e-3 << 1.76e-2 threshold (routing noise floor is ~4e-3 anyway).
// 2 MFMA/slot (was 3) and HALF the B traffic vs round 6; transpose uses a
// 16 KB buffer (4 passes x 16 rows) -> LDS 39424 B -> 4 blocks/CU.
// Batch scramble (faithful to reference reshape): i_x = b'>>1, b_x=((b'&1)<<3)+i.

typedef __attribute__((ext_vector_type(8))) _Float16 half8;
typedef __attribute__((ext_vector_type(4))) _Float16 half4;
typedef __attribute__((ext_vector_type(4))) float f32x4;

// W [400][256] fp32 -> Bh [52 kgroups][256 n][8 k] fp16, k padded 400->416.
__global__ void prep_w(const float* __restrict__ wg, _Float16* __restrict__ bh) {
    int k = blockIdx.x;        // 0..415
    int n = threadIdx.x;       // 0..255
    float f = (k < 400) ? wg[k * 256 + n] : 0.0f;
    bh[(k >> 3) * 2048 + n * 8 + (k & 7)] = (_Float16)f;
}

// DPP helpers: row = 16 lanes on CDNA. 0xB1 = quad_perm xor1, 0x4E = xor2,
// 0x124 = row_ror:4, 0x128 = row_ror:8 (ror8 == xor8 on a 16-ring).
template<int CTRL>
__device__ __forceinline__ float dppf(float x) {
    return __int_as_float(__builtin_amdgcn_update_dpp(
        0, __float_as_int(x), CTRL, 0xF, 0xF, true));
}
__device__ __forceinline__ float sum16(float x) {
    x += dppf<0xB1>(x);
    x += dppf<0x4E>(x);
    x += dppf<0x124>(x);
    x += dppf<0x128>(x);
    return x;
}

__global__ __launch_bounds__(256, 4) void caps_mfma_kernel(
    const float* __restrict__ xg,        // [16,32,32,8,16]
    const _Float16* __restrict__ bhg,    // [52][256][8]
    const float* __restrict__ bg,        // [256]
    float* __restrict__ outg)            // [16,32,32,16,16]
{
    __shared__ __align__(16) char buf[31232];  // xs_h+xs_l / vt (16384)
    __shared__ float logit_s[1024];            // [q8][i8][o16]
    __shared__ float route_s[1024];            // [q8][o16][i8] (transposed)

    _Float16* xs_h = (_Float16*)buf;           // [i8][rc 61][c16]
    _Float16* xs_l = (_Float16*)(buf + 15616);
    float*    vt   = (float*)buf;              // votes^T [n256][r16], swizzled

    const int t      = threadIdx.x;
    const int blk    = blockIdx.x;             // 2048
    const int wt     = blk & 3;
    const int h0     = (blk >> 2) & 31;
    const int bp     = blk >> 7;
    const int w0base = wt << 3;
    const int i_x    = bp >> 1;
    const int bbase  = (bp & 1) << 3;

    const float bias_r = bg[t];

    // ---- stage x window (60 rc x 16 c x 8 i = 7680 floats) as 1920 float4
    const float4* x4 = (const float4*)xg;
    #pragma unroll
    for (int kk = 0; kk < 8; ++kk) {
        int idx4 = t + (kk << 8);
        if (idx4 < 1920) {
            int c2 = idx4 & 3;                 // c = c2*4
            int i  = (idx4 >> 2) & 7;
            int rc = idx4 >> 5;                // 0..59 = r*12 + cc
            int r  = rc / 12;
            int cc = rc - r * 12;
            int hh = h0 + r - 2;
            int ww = w0base + cc - 2;
            float4 f = make_float4(0.f, 0.f, 0.f, 0.f);
            if (hh >= 0 && hh < 32 && ww >= 0 && ww < 32)
                f = x4[((((bbase + i) * 32 + hh) * 32 + ww) * 8 + i_x) * 4 + c2];
            _Float16 hx = (_Float16)f.x, hy = (_Float16)f.y;
            _Float16 hz = (_Float16)f.z, hw = (_Float16)f.w;
            _Float16 lx = (_Float16)(f.x - (float)hx);
            _Float16 ly = (_Float16)(f.y - (float)hy);
            _Float16 lz = (_Float16)(f.z - (float)hz);
            _Float16 lw = (_Float16)(f.w - (float)hw);
            half4 h4, l4;
            h4.x = hx; h4.y = hy; h4.z = hz; h4.w = hw;
            l4.x = lx; l4.y = ly; l4.z = lz; l4.w = lw;
            int a = i * 976 + rc * 16 + c2 * 4;
            *(half4*)&xs_h[a] = h4;
            *(half4*)&xs_l[a] = l4;
        }
    }
    __syncthreads();

    // ---- MFMA conv
    const int wv   = t >> 6;
    const int lane = t & 63;
    const int lrow = lane & 15;     // m (and n) index within 16-tile
    const int h8   = lane >> 4;     // k-quarter 0..3
    const int ia   = lrow & 7;      // i of this A row
    const int qh   = lrow >> 3;     // q parity

    f32x4 acc[4][4];
    #pragma unroll
    for (int ms = 0; ms < 4; ++ms)
        #pragma unroll
        for (int nt = 0; nt < 4; ++nt)
            acc[ms][nt] = (f32x4){0.f, 0.f, 0.f, 0.f};

    const half8* bhp = (const half8*)bhg;   // [52][256] half8

#define CONV_CHUNK(CH, TAIL)                                                   \
    {                                                                          \
        int k  = (CH) * 32 + h8 * 8;                                           \
        int p  = k >> 4;                                                       \
        int kh = p / 5;                                                        \
        int kw = p - kh * 5;                                                   \
        int c0 = k & 15;                                                       \
        int abase = ia * 976 + (kh * 12 + kw + qh) * 16 + c0;                  \
        int g = (CH) * 4 + h8;                                                 \
        half8 bhv[4];                                                          \
        _Pragma("unroll")                                                      \
        for (int nt = 0; nt < 4; ++nt) {                                       \
            int n = wv * 64 + nt * 16 + lrow;                                  \
            bhv[nt] = bhp[g * 256 + n];                                        \
        }                                                                      \
        _Pragma("unroll")                                                      \
        for (int ms = 0; ms < 4; ++ms) {                                       \
            half8 ahv, alv;                                                    \
            if (!(TAIL) || h8 < 2) {                                           \
                ahv = *(const half8*)&xs_h[abase + ms * 32];                   \
                alv = *(const half8*)&xs_l[abase + ms * 32];                   \
            } else { ahv = (half8)(_Float16)0.f; alv = (half8)(_Float16)0.f; } \
            _Pragma("unroll")                                                  \
            for (int nt = 0; nt < 4; ++nt) {                                   \
                acc[ms][nt] = __builtin_amdgcn_mfma_f32_16x16x32_f16(ahv, bhv[nt], acc[ms][nt], 0, 0, 0); \
                acc[ms][nt] = __builtin_amdgcn_mfma_f32_16x16x32_f16(alv, bhv[nt], acc[ms][nt], 0, 0, 0); \
            }                                                                  \
        }                                                                      \
    }

    #pragma unroll
    for (int ch = 0; ch < 12; ++ch) CONV_CHUNK(ch, false)
    CONV_CHUNK(12, true)
#undef CONV_CHUNK

    // ---- transpose acc -> v[q][i] regs, 4 passes of 16 rows via 16 KB vt.
    // Pass ms: rows r_local = h8*4+reg; vt dword addr = n*16 + ((rb^(n&3))<<2).
    float v[8][8];
    #pragma unroll
    for (int ms = 0; ms < 4; ++ms) {
        __syncthreads();                       // xs / previous-pass reads done
        #pragma unroll
        for (int nt = 0; nt < 4; ++nt) {
            int n = wv * 64 + nt * 16 + lrow;
            *(f32x4*)&vt[n * 16 + ((h8 ^ (n & 3)) << 2)] = acc[ms][nt];
        }
        __syncthreads();
        #pragma unroll
        for (int rb = 0; rb < 4; ++rb) {
            f32x4 x = *(const f32x4*)&vt[t * 16 + ((rb ^ (t & 3)) << 2)];
            int q  = ms * 2 + (rb >> 1);
            int ib = (rb & 1) * 4;
            v[q][ib + 0] = x[0];
            v[q][ib + 1] = x[1];
            v[q][ib + 2] = x[2];
            v[q][ib + 3] = x[3];
        }
    }

    // ---- routing from registers: thread t owns od=t (o=t>>4, d=t&15).
    const int o = t >> 4;
    const int d = t & 15;
    const bool b8  = (d & 8) != 0;
    const bool b2v = (d & 2) != 0;
    const bool b1v = (d & 1) != 0;
    const int  im  = (b8 ? 4 : 0) + (b2v ? 2 : 0) + (b1v ? 1 : 0);
    const bool wr  = (d & 4) == 0;
    float act_r[8];

    // agreement: 8 dot-sums over 16 lanes; DPP reduce-scatter, one ds_swizzle
    auto agree = [&](const float* vq, float act, int q, bool first) {
        float p[8];
        #pragma unroll
        for (int i = 0; i < 8; ++i) p[i] = vq[i] * act;
        float s4[4];
        #pragma unroll
        for (int j = 0; j < 4; ++j) {          // exchange lane^8 (ror8)
            float send = b8 ? p[j] : p[j + 4];
            float rcv  = dppf<0x128>(send);
            s4[j] = (b8 ? p[j + 4] : p[j]) + rcv;
        }
        float s2[2];
        #pragma unroll
        for (int j = 0; j < 2; ++j) {          // exchange lane^2
            float send = b2v ? s4[j] : s4[j + 2];
            float rcv  = dppf<0x4E>(send);
            s2[j] = (b2v ? s4[j + 2] : s4[j]) + rcv;
        }
        float send = b1v ? s2[0] : s2[1];      // exchange lane^1
        float rcv  = dppf<0xB1>(send);
        float s1 = (b1v ? s2[1] : s2[0]) + rcv;
        // final: exchange lane^4 (the one non-DPP involution) via ds_swizzle
        float L = s1 + __int_as_float(
            __builtin_amdgcn_ds_swizzle(__float_as_int(s1), 0x101F));
        if (wr) {
            float* dst = &logit_s[q * 128 + im * 16 + o];
            if (first) *dst = L; else *dst += L;
        }
    };

    // ---- it = 0: route == 1/16 exactly; logits written with '=' (no init).
    #pragma unroll
    for (int q = 0; q < 8; ++q) {
        float s = 0.0f;
        #pragma unroll
        for (int i = 0; i < 8; ++i) s += v[q][i];
        float pre = bias_r + 0.0625f * s;
        float n2 = sum16(pre * pre);
        float act = pre * sqrtf(n2) * __builtin_amdgcn_rcpf(1.0f + n2);
        act_r[q] = act;
        agree(v[q], act, q, true);
    }
    __syncthreads();

    // ---- it = 1, 2
    #pragma unroll
    for (int it = 1; it < 3; ++it) {
        {   // parallel softmax: thread -> row r = t>>2 (q=r>>3,i=r&7), 4 o's
            int rr = t >> 2, sq = rr >> 3, si = rr & 7, sj = t & 3;
            f32x4 lg = *(const f32x4*)&logit_s[rr * 16 + sj * 4];
            float m = fmaxf(fmaxf(lg[0], lg[1]), fmaxf(lg[2], lg[3]));
            m = fmaxf(m, dppf<0xB1>(m));       // quad max (4 lanes = same row)
            m = fmaxf(m, dppf<0x4E>(m));
            float e0 = __expf(lg[0] - m), e1 = __expf(lg[1] - m);
            float e2 = __expf(lg[2] - m), e3 = __expf(lg[3] - m);
            float ss = e0 + e1 + e2 + e3;
            ss += dppf<0xB1>(ss);
            ss += dppf<0x4E>(ss);
            float inv = __builtin_amdgcn_rcpf(ss);
            float* rt = &route_s[sq * 128 + si];
            rt[(sj * 4 + 0) * 8] = e0 * inv;
            rt[(sj * 4 + 1) * 8] = e1 * inv;
            rt[(sj * 4 + 2) * 8] = e2 * inv;
            rt[(sj * 4 + 3) * 8] = e3 * inv;
        }
        __syncthreads();

        #pragma unroll
        for (int q = 0; q < 8; ++q) {
            const f32x4* rp = (const f32x4*)&route_s[q * 128 + o * 8];
            f32x4 ra = rp[0], rb2 = rp[1];
            float pre = bias_r
                + ra[0] * v[q][0] + ra[1] * v[q][1] + ra[2] * v[q][2] + ra[3] * v[q][3]
                + rb2[0] * v[q][4] + rb2[1] * v[q][5] + rb2[2] * v[q][6] + rb2[3] * v[q][7];
            float n2 = sum16(pre * pre);
            float act = pre * sqrtf(n2) * __builtin_amdgcn_rcpf(1.0f + n2);
            act_r[q] = act;
            if (it == 1) agree(v[q], act, q, false);
        }
        if (it == 1) __syncthreads();
    }

    // ---- output [b',h0,w0base+q,o,d]
    #pragma unroll
    for (int q = 0; q < 8; ++q)
        outg[((bp * 32 + h0) * 32 + (w0base + q)) * 256 + t] = act_r[q];
}

extern "C" void kernel_launch(void* const* d_in, const int* in_sizes, int n_in,
                              void* d_out, int out_size, void* d_ws, size_t ws_size,
                              hipStream_t stream) {
    const float* x = (const float*)d_in[0];
    const float* w = (const float*)d_in[1];
    const float* b = (const float*)d_in[2];
    float* out = (float*)d_out;

    _Float16* bh = (_Float16*)d_ws;            // 52*256*8*2 = 106496 B

    hipLaunchKernelGGL(prep_w, dim3(416), dim3(256), 0, stream, w, bh);
    hipLaunchKernelGGL(caps_mfma_kernel, dim3(2048), dim3(256), 0, stream,
                       x, bh, b, out);
}